// Round 3
// baseline (2776.851 us; speedup 1.0000x reference)
//
#include <hip/hip_runtime.h>
#include <math.h>

#define BATCH 8
#define NPTS 2048
#define MPTS 2048
#define ROWS_PER_BLK 16
#define CHUNKS (NPTS/ROWS_PER_BLK)   // 128
#define NBLK (BATCH*CHUNKS)          // 1024
#define KS (MPTS/64)                 // 32 columns per lane

// Persistent state (re-initialized every kernel_launch -> deterministic).
__device__ float  g_remainl[BATCH*NPTS];
__device__ float  g_s[BATCH*NPTS];
__device__ float  g_remainr[BATCH*MPTS];
__device__ float  g_colsum[BATCH*MPTS];
__device__ float2 g_pr[BATCH*MPTS];   // (p = rr*ratio, rr_new)
__device__ float  g_cost;

#if __has_builtin(__builtin_amdgcn_exp2f)
#define EXP2(x) __builtin_amdgcn_exp2f(x)
#else
#define EXP2(x) exp2f(x)
#endif
#if __has_builtin(__builtin_amdgcn_sqrtf)
#define FSQRT(x) __builtin_amdgcn_sqrtf(x)
#else
#define FSQRT(x) sqrtf(x)
#endif

__global__ __launch_bounds__(256) void k_init() {
  int i = blockIdx.x*256 + threadIdx.x;   // 64 x 256 = 16384
  g_remainl[i] = 1.0f;    // factorl = 1 (n == m)
  g_remainr[i] = 1.0f;
  g_colsum[i]  = 0.0f;
  if (i == 0) g_cost = 0.0f;
}

// A-part for level 0 only (remainl = remainr = 1).
__global__ __launch_bounds__(256, 4) void k_a0(const float* __restrict__ gen,
                                               const float* __restrict__ gt,
                                               float c1) {
  const int blk = blockIdx.x, b = blk >> 7, chunk = blk & 127;
  const int t = threadIdx.x, wave = t >> 6, lane = t & 63;
  __shared__ float smem[10240];          // 40 KB exactly (4 blocks/CU)
  float* gtx = smem; float* gty = smem + 2048; float* gtz = smem + 4096;
  for (int i = t; i < MPTS; i += 256) {
    gtx[i] = gt[(b*MPTS+i)*3+0];
    gty[i] = gt[(b*MPTS+i)*3+1];
    gtz[i] = gt[(b*MPTS+i)*3+2];
  }
  __syncthreads();
  float w[KS], colacc[KS];
  #pragma unroll
  for (int k = 0; k < KS; ++k) colacc[k] = 0.f;
  for (int r = 0; r < 4; ++r) {
    const int n = chunk*ROWS_PER_BLK + wave*4 + r;
    const int idx = b*NPTS + n;
    const float gx = gen[idx*3+0], gy = gen[idx*3+1], gz = gen[idx*3+2];
    float rowsum = 0.f;
    #pragma unroll
    for (int k = 0; k < KS; ++k) {
      const int m = lane + 64*k;
      const float dx = gx - gtx[m], dy = gy - gty[m], dz = gz - gtz[m];
      const float d2 = dx*dx + dy*dy + dz*dz;
      const float e = EXP2(c1*d2);
      w[k] = e; rowsum += e;
    }
    #pragma unroll
    for (int off = 1; off < 64; off <<= 1) rowsum += __shfl_xor(rowsum, off);
    const float sc = 1.0f / (rowsum + 1e-9f);
    if (lane == 0) g_s[idx] = sc;
    #pragma unroll
    for (int k = 0; k < KS; ++k) colacc[k] = fmaf(w[k], sc, colacc[k]);
  }
  __syncthreads();                       // reuse smem as per-wave colsum
  float* scol = smem + wave*2048;
  #pragma unroll
  for (int k = 0; k < KS; ++k) scol[lane + 64*k] = colacc[k];
  __syncthreads();
  for (int i = t; i < MPTS; i += 256) {
    const float v = smem[i] + smem[2048+i] + smem[4096+i] + smem[6144+i];
    atomicAdd(&g_colsum[b*MPTS+i], v);
  }
}

// B: column saturation; packs (p, rr_new) for the next kernel; resets colsum.
__global__ __launch_bounds__(256) void k_cols() {
  const int i = blockIdx.x*256 + threadIdx.x;
  const float cs = g_colsum[i];
  const float rr = g_remainr[i];
  const float ratio = fminf(rr / (cs + 1e-9f), 1.0f);
  const float rrn = fmaxf(rr - cs*ratio, 0.0f);
  g_pr[i] = make_float2(rr*ratio, rrn);
  g_remainr[i] = rrn;
  g_colsum[i] = 0.0f;
}

// Fused C(level l) + A(level l+1): one d2 per element, e2 = exp2(lr * t1)
// since level_{l+1} = level_l / 4 (lr = 0.25; lr = 0 for the last pair).
__global__ __launch_bounds__(256, 4) void k_ca(const float* __restrict__ gen,
                                               const float* __restrict__ gt,
                                               float c1, float lr) {
  const int blk = blockIdx.x, b = blk >> 7, chunk = blk & 127;
  const int t = threadIdx.x, wave = t >> 6, lane = t & 63;
  __shared__ float smem[10240];          // 40 KB: gt planar 24K + pr 16K; col alias
  float* gtx = smem; float* gty = smem + 2048; float* gtz = smem + 4096;
  float2* spr = (float2*)(smem + 6144);
  for (int i = t; i < MPTS; i += 256) {
    gtx[i] = gt[(b*MPTS+i)*3+0];
    gty[i] = gt[(b*MPTS+i)*3+1];
    gtz[i] = gt[(b*MPTS+i)*3+2];
    spr[i] = g_pr[b*MPTS+i];
  }
  __syncthreads();
  float w[KS], colacc[KS];
  #pragma unroll
  for (int k = 0; k < KS; ++k) colacc[k] = 0.f;
  float costacc = 0.f;
  for (int r = 0; r < 4; ++r) {
    const int n = chunk*ROWS_PER_BLK + wave*4 + r;
    const int idx = b*NPTS + n;
    const float gx = gen[idx*3+0], gy = gen[idx*3+1], gz = gen[idx*3+2];
    const float sc = g_s[idx];
    const float rl = g_remainl[idx];
    float s1 = 0.f, s2 = 0.f, rsn = 0.f;
    #pragma unroll
    for (int k = 0; k < KS; ++k) {
      const int m = lane + 64*k;
      const float dx = gx - gtx[m], dy = gy - gty[m], dz = gz - gtz[m];
      const float d2 = dx*dx + dy*dy + dz*dz;
      const float2 pr = spr[m];
      const float t1 = c1*d2;
      const float e1 = EXP2(t1);
      const float u  = e1*pr.x;          // exp(l*d2) * p
      s1 += u;
      s2 = fmaf(u, FSQRT(fmaxf(d2, 1e-20f)), s2);
      const float e2 = EXP2(lr*t1);      // next level's exp
      const float wn = e2*pr.y;
      w[k] = wn; rsn += wn;
    }
    costacc = fmaf(sc, s2, costacc);     // lane-partial; reduced once at end
    #pragma unroll
    for (int off = 1; off < 64; off <<= 1) {
      s1  += __shfl_xor(s1, off);
      rsn += __shfl_xor(rsn, off);
    }
    const float rowsum2 = sc*s1;
    const float rl_new  = fmaxf(rl - rowsum2, 0.0f);
    const float sc_next = rl_new / (rsn + 1e-9f);
    if (lane == 0) { g_remainl[idx] = rl_new; g_s[idx] = sc_next; }
    #pragma unroll
    for (int k = 0; k < KS; ++k) colacc[k] = fmaf(w[k], sc_next, colacc[k]);
  }
  #pragma unroll
  for (int off = 1; off < 64; off <<= 1) costacc += __shfl_xor(costacc, off);
  __syncthreads();                       // all reads of gt/pr done; reuse smem
  float* scol = smem + wave*2048;
  #pragma unroll
  for (int k = 0; k < KS; ++k) scol[lane + 64*k] = colacc[k];
  if (lane == 0) smem[8192 + wave] = costacc;
  __syncthreads();
  for (int i = t; i < MPTS; i += 256) {
    const float v = smem[i] + smem[2048+i] + smem[4096+i] + smem[6144+i];
    atomicAdd(&g_colsum[b*MPTS+i], v);
  }
  if (t == 0)
    atomicAdd(&g_cost, smem[8192] + smem[8193] + smem[8194] + smem[8195]);
}

// C-part only for the final level (level == 0 -> exp term is exactly 1).
__global__ __launch_bounds__(256, 4) void k_c_last(const float* __restrict__ gen,
                                                   const float* __restrict__ gt) {
  const int blk = blockIdx.x, b = blk >> 7, chunk = blk & 127;
  const int t = threadIdx.x, wave = t >> 6, lane = t & 63;
  __shared__ float smem[10240];
  float* gtx = smem; float* gty = smem + 2048; float* gtz = smem + 4096;
  float2* spr = (float2*)(smem + 6144);
  for (int i = t; i < MPTS; i += 256) {
    gtx[i] = gt[(b*MPTS+i)*3+0];
    gty[i] = gt[(b*MPTS+i)*3+1];
    gtz[i] = gt[(b*MPTS+i)*3+2];
    spr[i] = g_pr[b*MPTS+i];
  }
  __syncthreads();
  float costacc = 0.f;
  for (int r = 0; r < 4; ++r) {
    const int n = chunk*ROWS_PER_BLK + wave*4 + r;
    const int idx = b*NPTS + n;
    const float gx = gen[idx*3+0], gy = gen[idx*3+1], gz = gen[idx*3+2];
    const float sc = g_s[idx];
    float s2 = 0.f;
    #pragma unroll
    for (int k = 0; k < KS; ++k) {
      const int m = lane + 64*k;
      const float dx = gx - gtx[m], dy = gy - gty[m], dz = gz - gtz[m];
      const float d2 = dx*dx + dy*dy + dz*dz;
      const float u = spr[m].x;          // exp(0*d2) == 1
      s2 = fmaf(u, FSQRT(fmaxf(d2, 1e-20f)), s2);
    }
    costacc = fmaf(sc, s2, costacc);
  }
  #pragma unroll
  for (int off = 1; off < 64; off <<= 1) costacc += __shfl_xor(costacc, off);
  if (lane == 0) smem[8192 + wave] = costacc;
  __syncthreads();
  if (t == 0)
    atomicAdd(&g_cost, smem[8192] + smem[8193] + smem[8194] + smem[8195]);
}

__global__ void k_final(float* __restrict__ out) {
  out[0] = g_cost * (1.0f / (float)(BATCH*NPTS));
}

extern "C" void kernel_launch(void* const* d_in, const int* in_sizes, int n_in,
                              void* d_out, int out_size, void* d_ws, size_t ws_size,
                              hipStream_t stream) {
  const float* gen = (const float*)d_in[0];   // pc_gen [8,2048,3] f32
  const float* gt  = (const float*)d_in[1];   // pc_gt  [8,2048,3] f32
  float* out = (float*)d_out;

  const double L[10] = {-16384.0, -4096.0, -1024.0, -256.0, -64.0,
                        -16.0, -4.0, -1.0, -0.25, 0.0};
  float c[10];
  for (int i = 0; i < 10; ++i) c[i] = (float)(L[i] * 1.4426950408889634);

  k_init<<<64, 256, 0, stream>>>();
  k_a0<<<NBLK, 256, 0, stream>>>(gen, gt, c[0]);
  for (int l = 0; l < 9; ++l) {
    k_cols<<<64, 256, 0, stream>>>();
    // level_{l+1}/level_l = 0.25 exactly for l<8; last pair targets level 0.
    k_ca<<<NBLK, 256, 0, stream>>>(gen, gt, c[l], (l < 8) ? 0.25f : 0.0f);
  }
  k_cols<<<64, 256, 0, stream>>>();
  k_c_last<<<NBLK, 256, 0, stream>>>(gen, gt);
  k_final<<<1, 1, 0, stream>>>(out);
}

// Round 4
// 573.128 us; speedup vs baseline: 4.8451x; 4.8451x over previous
//
#include <hip/hip_runtime.h>
#include <math.h>

#define BATCH 8
#define NPTS 2048
#define MPTS 2048
#define ROWS_PER_BLK 16
#define CHUNKS (NPTS/ROWS_PER_BLK)   // 128
#define NBLK (BATCH*CHUNKS)          // 1024
#define KS (MPTS/64)                 // 32 columns per lane

// Persistent state (re-initialized every kernel_launch -> deterministic).
__device__ float  g_remainl[BATCH*NPTS];
__device__ float  g_s[BATCH*NPTS];
__device__ float  g_remainr[BATCH*MPTS];
__device__ float  g_colsum[BATCH*MPTS];
__device__ float2 g_pr[BATCH*MPTS];   // (p = rr*ratio, rr_new)
__device__ float  g_cost;

#if __has_builtin(__builtin_amdgcn_exp2f)
#define EXP2(x) __builtin_amdgcn_exp2f(x)
#else
#define EXP2(x) exp2f(x)
#endif
#if __has_builtin(__builtin_amdgcn_sqrtf)
#define FSQRT(x) __builtin_amdgcn_sqrtf(x)
#else
#define FSQRT(x) sqrtf(x)
#endif

__global__ __launch_bounds__(256) void k_init() {
  int i = blockIdx.x*256 + threadIdx.x;   // 64 x 256 = 16384
  g_remainl[i] = 1.0f;    // factorl = 1 (n == m)
  g_remainr[i] = 1.0f;
  g_colsum[i]  = 0.0f;
  if (i == 0) g_cost = 0.0f;
}

// A-part for level 0 only (remainl = remainr = 1).
__global__ __launch_bounds__(256) void k_a0(const float* __restrict__ gen,
                                            const float* __restrict__ gt,
                                            float c1) {
  const int blk = blockIdx.x, b = blk >> 7, chunk = blk & 127;
  const int t = threadIdx.x, wave = t >> 6, lane = t & 63;
  __shared__ __align__(16) float smem[10240];   // 40 KB
  float4* sgt = (float4*)smem;                  // [2048] (x,y,z,-) : 32 KB
  for (int i = t; i < MPTS; i += 256) {
    const int gi = (b*MPTS + i)*3;
    sgt[i] = make_float4(gt[gi+0], gt[gi+1], gt[gi+2], 0.f);
  }
  __syncthreads();
  float w[KS], colacc[KS];
  #pragma unroll
  for (int k = 0; k < KS; ++k) colacc[k] = 0.f;
  #pragma unroll 1
  for (int r = 0; r < 4; ++r) {
    const int n = chunk*ROWS_PER_BLK + wave*4 + r;
    const int idx = b*NPTS + n;
    const float gx = gen[idx*3+0], gy = gen[idx*3+1], gz = gen[idx*3+2];
    float rowsum = 0.f;
    #pragma unroll
    for (int k = 0; k < KS; ++k) {
      const int m = lane + 64*k;
      const float4 g4 = sgt[m];
      const float dx = gx - g4.x, dy = gy - g4.y, dz = gz - g4.z;
      const float d2 = dx*dx + dy*dy + dz*dz;
      const float e = EXP2(c1*d2);
      w[k] = e; rowsum += e;
    }
    #pragma unroll
    for (int off = 1; off < 64; off <<= 1) rowsum += __shfl_xor(rowsum, off);
    const float sc = 1.0f / (rowsum + 1e-9f);
    if (lane == 0) g_s[idx] = sc;
    #pragma unroll
    for (int k = 0; k < KS; ++k) colacc[k] = fmaf(w[k], sc, colacc[k]);
  }
  __syncthreads();                       // reuse smem as per-wave colsum
  float* scol = smem + wave*2048;
  #pragma unroll
  for (int k = 0; k < KS; ++k) scol[lane + 64*k] = colacc[k];
  __syncthreads();
  for (int i = t; i < MPTS; i += 256) {
    const float v = smem[i] + smem[2048+i] + smem[4096+i] + smem[6144+i];
    atomicAdd(&g_colsum[b*MPTS+i], v);
  }
}

// B: column saturation; packs (p, rr_new) for the next kernel; resets colsum.
__global__ __launch_bounds__(256) void k_cols() {
  const int i = blockIdx.x*256 + threadIdx.x;
  const float cs = g_colsum[i];
  const float rr = g_remainr[i];
  const float ratio = fminf(rr / (cs + 1e-9f), 1.0f);
  const float rrn = fmaxf(rr - cs*ratio, 0.0f);
  g_pr[i] = make_float2(rr*ratio, rrn);
  g_remainr[i] = rrn;
  g_colsum[i] = 0.0f;
}

// Fused C(level l) + A(level l+1): one d2 per element, e2 = exp2(lr * t1)
// since level_{l+1} = level_l / 4 (lr = 0.25; lr = 0 for the last pair).
// LDS: sgt[m] = (x, y, z, p) 32 KB  +  srr[m] = rr_new 8 KB. scol aliases after sync.
__global__ __launch_bounds__(256) void k_ca(const float* __restrict__ gen,
                                            const float* __restrict__ gt,
                                            float c1, float lr) {
  const int blk = blockIdx.x, b = blk >> 7, chunk = blk & 127;
  const int t = threadIdx.x, wave = t >> 6, lane = t & 63;
  __shared__ __align__(16) float smem[10240];   // 40 KB
  float4* sgt = (float4*)smem;                  // 32 KB
  float*  srr = smem + 8192;                    // 8 KB
  for (int i = t; i < MPTS; i += 256) {
    const int gi = (b*MPTS + i)*3;
    const float2 pr = g_pr[b*MPTS + i];
    sgt[i] = make_float4(gt[gi+0], gt[gi+1], gt[gi+2], pr.x);
    srr[i] = pr.y;
  }
  __syncthreads();
  float w[KS], colacc[KS];
  #pragma unroll
  for (int k = 0; k < KS; ++k) colacc[k] = 0.f;
  float costacc = 0.f;
  #pragma unroll 1
  for (int r = 0; r < 4; ++r) {
    const int n = chunk*ROWS_PER_BLK + wave*4 + r;
    const int idx = b*NPTS + n;
    const float gx = gen[idx*3+0], gy = gen[idx*3+1], gz = gen[idx*3+2];
    const float sc = g_s[idx];
    const float rl = g_remainl[idx];
    float s1 = 0.f, s2 = 0.f, rsn = 0.f;
    #pragma unroll
    for (int k = 0; k < KS; ++k) {
      const int m = lane + 64*k;
      const float4 g4 = sgt[m];
      const float rrn = srr[m];
      const float dx = gx - g4.x, dy = gy - g4.y, dz = gz - g4.z;
      const float d2 = dx*dx + dy*dy + dz*dz;
      const float t1 = c1*d2;
      const float u  = EXP2(t1)*g4.w;    // exp(l*d2) * p
      s1 += u;
      s2 = fmaf(u, FSQRT(fmaxf(d2, 1e-20f)), s2);
      const float wn = EXP2(lr*t1)*rrn;  // next level's pre-weight
      w[k] = wn; rsn += wn;
    }
    costacc = fmaf(sc, s2, costacc);     // lane-partial; reduced once at end
    #pragma unroll
    for (int off = 1; off < 64; off <<= 1) {
      s1  += __shfl_xor(s1, off);
      rsn += __shfl_xor(rsn, off);
    }
    const float rowsum2 = sc*s1;
    const float rl_new  = fmaxf(rl - rowsum2, 0.0f);
    const float sc_next = rl_new / (rsn + 1e-9f);
    if (lane == 0) { g_remainl[idx] = rl_new; g_s[idx] = sc_next; }
    #pragma unroll
    for (int k = 0; k < KS; ++k) colacc[k] = fmaf(w[k], sc_next, colacc[k]);
  }
  #pragma unroll
  for (int off = 1; off < 64; off <<= 1) costacc += __shfl_xor(costacc, off);
  __syncthreads();                       // all reads of sgt/srr done; reuse smem
  float* scol = smem + wave*2048;
  #pragma unroll
  for (int k = 0; k < KS; ++k) scol[lane + 64*k] = colacc[k];
  if (lane == 0) smem[8192 + wave] = costacc;
  __syncthreads();
  for (int i = t; i < MPTS; i += 256) {
    const float v = smem[i] + smem[2048+i] + smem[4096+i] + smem[6144+i];
    atomicAdd(&g_colsum[b*MPTS+i], v);
  }
  if (t == 0)
    atomicAdd(&g_cost, smem[8192] + smem[8193] + smem[8194] + smem[8195]);
}

// C-part only for the final level (level == 0 -> exp term is exactly 1).
__global__ __launch_bounds__(256) void k_c_last(const float* __restrict__ gen,
                                                const float* __restrict__ gt) {
  const int blk = blockIdx.x, b = blk >> 7, chunk = blk & 127;
  const int t = threadIdx.x, wave = t >> 6, lane = t & 63;
  __shared__ __align__(16) float smem[10240];
  float4* sgt = (float4*)smem;                  // (x,y,z,p) : 32 KB
  for (int i = t; i < MPTS; i += 256) {
    const int gi = (b*MPTS + i)*3;
    sgt[i] = make_float4(gt[gi+0], gt[gi+1], gt[gi+2], g_pr[b*MPTS + i].x);
  }
  __syncthreads();
  float costacc = 0.f;
  #pragma unroll 1
  for (int r = 0; r < 4; ++r) {
    const int n = chunk*ROWS_PER_BLK + wave*4 + r;
    const int idx = b*NPTS + n;
    const float gx = gen[idx*3+0], gy = gen[idx*3+1], gz = gen[idx*3+2];
    const float sc = g_s[idx];
    float s2 = 0.f;
    #pragma unroll
    for (int k = 0; k < KS; ++k) {
      const int m = lane + 64*k;
      const float4 g4 = sgt[m];
      const float dx = gx - g4.x, dy = gy - g4.y, dz = gz - g4.z;
      const float d2 = dx*dx + dy*dy + dz*dz;
      s2 = fmaf(g4.w, FSQRT(fmaxf(d2, 1e-20f)), s2);   // exp(0)=1
    }
    costacc = fmaf(sc, s2, costacc);
  }
  #pragma unroll
  for (int off = 1; off < 64; off <<= 1) costacc += __shfl_xor(costacc, off);
  if (lane == 0) smem[8192 + wave] = costacc;
  __syncthreads();
  if (t == 0)
    atomicAdd(&g_cost, smem[8192] + smem[8193] + smem[8194] + smem[8195]);
}

__global__ void k_final(float* __restrict__ out) {
  out[0] = g_cost * (1.0f / (float)(BATCH*NPTS));
}

extern "C" void kernel_launch(void* const* d_in, const int* in_sizes, int n_in,
                              void* d_out, int out_size, void* d_ws, size_t ws_size,
                              hipStream_t stream) {
  const float* gen = (const float*)d_in[0];   // pc_gen [8,2048,3] f32
  const float* gt  = (const float*)d_in[1];   // pc_gt  [8,2048,3] f32
  float* out = (float*)d_out;

  const double L[10] = {-16384.0, -4096.0, -1024.0, -256.0, -64.0,
                        -16.0, -4.0, -1.0, -0.25, 0.0};
  float c[10];
  for (int i = 0; i < 10; ++i) c[i] = (float)(L[i] * 1.4426950408889634);

  k_init<<<64, 256, 0, stream>>>();
  k_a0<<<NBLK, 256, 0, stream>>>(gen, gt, c[0]);
  for (int l = 0; l < 9; ++l) {
    k_cols<<<64, 256, 0, stream>>>();
    // level_{l+1}/level_l = 0.25 exactly for l<8; last pair targets level 0.
    k_ca<<<NBLK, 256, 0, stream>>>(gen, gt, c[l], (l < 8) ? 0.25f : 0.0f);
  }
  k_cols<<<64, 256, 0, stream>>>();
  k_c_last<<<NBLK, 256, 0, stream>>>(gen, gt);
  k_final<<<1, 1, 0, stream>>>(out);
}

// Round 5
// 423.965 us; speedup vs baseline: 6.5497x; 1.3518x over previous
//
#include <hip/hip_runtime.h>
#include <math.h>

#define BATCH 8
#define NPTS 2048
#define MPTS 2048
#define TPB 512                       // 8 waves
#define RPB 16                        // rows per block
#define KC 4                          // columns per thread: 2048/512
#define CHUNKS (NPTS/RPB)             // 128
#define NBLK (BATCH*CHUNKS)           // 1024

// Persistent state (re-initialized every kernel_launch -> deterministic).
__device__ float  g_remainl[BATCH*NPTS];
__device__ float  g_s[BATCH*NPTS];
__device__ float  g_remainr[BATCH*MPTS];
__device__ float  g_colsum[BATCH*MPTS];
__device__ float2 g_pr[BATCH*MPTS];   // (p = rr*ratio, rr_new)
__device__ float  g_cost;

#if __has_builtin(__builtin_amdgcn_exp2f)
#define EXP2(x) __builtin_amdgcn_exp2f(x)
#else
#define EXP2(x) exp2f(x)
#endif
#if __has_builtin(__builtin_amdgcn_sqrtf)
#define FSQRT(x) __builtin_amdgcn_sqrtf(x)
#else
#define FSQRT(x) sqrtf(x)
#endif

__global__ __launch_bounds__(256) void k_init() {
  int i = blockIdx.x*256 + threadIdx.x;   // 64 x 256
  g_remainl[i] = 1.0f;    // factorl = 1 (n == m)
  g_remainr[i] = 1.0f;
  g_colsum[i]  = 0.0f;
  if (i == 0) g_cost = 0.0f;
}

// B: column saturation; packs (p, rr_new); resets colsum.
__global__ __launch_bounds__(256) void k_cols() {
  const int i = blockIdx.x*256 + threadIdx.x;
  const float cs = g_colsum[i];
  const float rr = g_remainr[i];
  const float ratio = fminf(rr / (cs + 1e-9f), 1.0f);
  const float rrn = fmaxf(rr - cs*ratio, 0.0f);
  g_pr[i] = make_float2(rr*ratio, rrn);
  g_remainr[i] = rrn;
  g_colsum[i] = 0.0f;
}

// Each thread owns KC=4 fixed columns (register-resident). d2 via
// |g|^2+|c|^2-2g.c with per-row constants (-2gx,-2gy,-2gz,|g|^2) in LDS.
#define STAGE_COLS(NEED_PR)                                                \
  float cx[KC], cy[KC], cz[KC], rc2[KC], pp[KC], rrn[KC];                  \
  _Pragma("unroll")                                                        \
  for (int k = 0; k < KC; ++k) {                                           \
    const int m = t + TPB*k;                                               \
    const int gi = (b*MPTS + m)*3;                                         \
    cx[k] = gt[gi+0]; cy[k] = gt[gi+1]; cz[k] = gt[gi+2];                  \
    rc2[k] = cx[k]*cx[k] + cy[k]*cy[k] + cz[k]*cz[k];                      \
    if (NEED_PR) { const float2 pr = g_pr[b*MPTS + m];                     \
                   pp[k] = pr.x; rrn[k] = pr.y; }                          \
    else { pp[k] = 1.f; rrn[k] = 1.f; }                                    \
  }

#define STAGE_ROWS()                                                       \
  if (t < RPB) {                                                           \
    const int gi = (rowbase + t)*3;                                        \
    const float px = gen[gi+0], py = gen[gi+1], pz = gen[gi+2];            \
    rowdat[t] = make_float4(-2.f*px, -2.f*py, -2.f*pz,                     \
                            px*px + py*py + pz*pz);                        \
  }

#define D2(rd, k) fmaf(rd.x, cx[k], fmaf(rd.y, cy[k],                      \
                   fmaf(rd.z, cz[k], rd.w + rc2[k])))

// A-part for the first level (remainl = remainr = 1).
__global__ __launch_bounds__(TPB) void k_a0(const float* __restrict__ gen,
                                            const float* __restrict__ gt,
                                            float c1) {
  const int blk = blockIdx.x, b = blk >> 7, chunk = blk & (CHUNKS-1);
  const int t = threadIdx.x, wave = t >> 6, lane = t & 63;
  const int rowbase = b*NPTS + chunk*RPB;
  __shared__ float4 rowdat[RPB];
  __shared__ float  red[RPB][8];
  __shared__ float  scn_s[RPB];
  STAGE_COLS(false)
  STAGE_ROWS()
  __syncthreads();
  #pragma unroll 1
  for (int r = 0; r < RPB; ++r) {
    const float4 rd = rowdat[r];
    float s1 = 0.f;
    #pragma unroll
    for (int k = 0; k < KC; ++k) s1 += EXP2(c1*D2(rd, k));
    #pragma unroll
    for (int off = 1; off < 64; off <<= 1) s1 += __shfl_xor(s1, off);
    if (lane == 0) red[r][wave] = s1;
  }
  __syncthreads();
  if (wave == 0 && lane < RPB) {
    float s1t = 0.f;
    #pragma unroll
    for (int w = 0; w < 8; ++w) s1t += red[lane][w];
    const float sc = 1.0f / (s1t + 1e-9f);
    g_s[rowbase + lane] = sc;
    scn_s[lane] = sc;
  }
  __syncthreads();
  float colacc[KC] = {0.f, 0.f, 0.f, 0.f};
  #pragma unroll 1
  for (int r = 0; r < RPB; ++r) {
    const float4 rd = rowdat[r];
    const float scn = scn_s[r];
    #pragma unroll
    for (int k = 0; k < KC; ++k)
      colacc[k] = fmaf(EXP2(c1*D2(rd, k)), scn, colacc[k]);
  }
  #pragma unroll
  for (int k = 0; k < KC; ++k)
    atomicAdd(&g_colsum[b*MPTS + t + TPB*k], colacc[k]);   // rr == 1
}

// Fused C(level l) + A(level l+1). eq = exp2(cq*d2) is the NEXT level's
// weight; e1 = eq^4 = exp2(c1*d2) (c1 = 4*cq exactly). LAST: next level
// is 0 -> e=1, pass2 collapses.
template<bool LAST>
__global__ __launch_bounds__(TPB) void k_ca(const float* __restrict__ gen,
                                            const float* __restrict__ gt,
                                            float c1, float cq) {
  const int blk = blockIdx.x, b = blk >> 7, chunk = blk & (CHUNKS-1);
  const int t = threadIdx.x, wave = t >> 6, lane = t & 63;
  const int rowbase = b*NPTS + chunk*RPB;
  __shared__ float4 rowdat[RPB];
  __shared__ float4 red[RPB][8];
  __shared__ float  scn_s[RPB];
  STAGE_COLS(true)
  STAGE_ROWS()
  __syncthreads();
  // pass1: per-row s1 (mass), s2 (cost), rsn (next-level rowsum)
  #pragma unroll 1
  for (int r = 0; r < RPB; ++r) {
    const float4 rd = rowdat[r];
    float s1 = 0.f, s2 = 0.f, rsn = 0.f;
    #pragma unroll
    for (int k = 0; k < KC; ++k) {
      const float d2 = D2(rd, k);
      float e1;
      if (LAST) {
        e1 = EXP2(c1*d2);
        rsn += rrn[k];                       // next-level e == 1
      } else {
        const float eq = EXP2(cq*d2);
        const float e2 = eq*eq;
        e1 = e2*e2;
        rsn = fmaf(eq, rrn[k], rsn);
      }
      const float u = e1*pp[k];
      s1 += u;
      s2 = fmaf(u, FSQRT(fmaxf(d2, 1e-20f)), s2);
    }
    #pragma unroll
    for (int off = 1; off < 64; off <<= 1) {
      s1  += __shfl_xor(s1, off);
      s2  += __shfl_xor(s2, off);
      rsn += __shfl_xor(rsn, off);
    }
    if (lane == 0) red[r][wave] = make_float4(s1, s2, rsn, 0.f);
  }
  __syncthreads();
  // mid-phase: per-row scalars (16 lanes of wave 0)
  if (wave == 0 && lane < RPB) {
    float s1t = 0.f, s2t = 0.f, rst = 0.f;
    #pragma unroll
    for (int w = 0; w < 8; ++w) {
      const float4 v = red[lane][w];
      s1t += v.x; s2t += v.y; rst += v.z;
    }
    const int idx = rowbase + lane;
    const float sc = g_s[idx];
    const float rl = g_remainl[idx];
    const float rl_new = fmaxf(rl - sc*s1t, 0.0f);
    const float scn = rl_new / (rst + 1e-9f);
    g_remainl[idx] = rl_new;
    g_s[idx] = scn;
    scn_s[lane] = scn;
    float cost = sc*s2t;
    #pragma unroll
    for (int off = 1; off < RPB; off <<= 1) cost += __shfl_xor(cost, off);
    if (lane == 0) atomicAdd(&g_cost, cost);
  }
  __syncthreads();
  // pass2: colsum for the NEXT level: colsum[m] = rrn[m] * sum_r scn[r]*eq
  if (LAST) {
    float st = 0.f;
    #pragma unroll
    for (int r = 0; r < RPB; ++r) st += scn_s[r];
    #pragma unroll
    for (int k = 0; k < KC; ++k)
      atomicAdd(&g_colsum[b*MPTS + t + TPB*k], rrn[k]*st);
  } else {
    float colacc[KC] = {0.f, 0.f, 0.f, 0.f};
    #pragma unroll 1
    for (int r = 0; r < RPB; ++r) {
      const float4 rd = rowdat[r];
      const float scn = scn_s[r];
      #pragma unroll
      for (int k = 0; k < KC; ++k)
        colacc[k] = fmaf(EXP2(cq*D2(rd, k)), scn, colacc[k]);
    }
    #pragma unroll
    for (int k = 0; k < KC; ++k)
      atomicAdd(&g_colsum[b*MPTS + t + TPB*k], colacc[k]*rrn[k]);
  }
}

// C-part of the final level (level == 0 -> weight = p, no exp).
__global__ __launch_bounds__(TPB) void k_c_last(const float* __restrict__ gen,
                                                const float* __restrict__ gt) {
  const int blk = blockIdx.x, b = blk >> 7, chunk = blk & (CHUNKS-1);
  const int t = threadIdx.x, wave = t >> 6, lane = t & 63;
  const int rowbase = b*NPTS + chunk*RPB;
  __shared__ float4 rowdat[RPB];
  __shared__ float  red[RPB][8];
  STAGE_COLS(true)
  STAGE_ROWS()
  __syncthreads();
  #pragma unroll 1
  for (int r = 0; r < RPB; ++r) {
    const float4 rd = rowdat[r];
    float s2 = 0.f;
    #pragma unroll
    for (int k = 0; k < KC; ++k)
      s2 = fmaf(pp[k], FSQRT(fmaxf(D2(rd, k), 1e-20f)), s2);
    #pragma unroll
    for (int off = 1; off < 64; off <<= 1) s2 += __shfl_xor(s2, off);
    if (lane == 0) red[r][wave] = s2;
  }
  __syncthreads();
  if (wave == 0 && lane < RPB) {
    float s2t = 0.f;
    #pragma unroll
    for (int w = 0; w < 8; ++w) s2t += red[lane][w];
    float cost = g_s[rowbase + lane] * s2t;
    #pragma unroll
    for (int off = 1; off < RPB; off <<= 1) cost += __shfl_xor(cost, off);
    if (lane == 0) atomicAdd(&g_cost, cost);
  }
}

__global__ void k_final(float* __restrict__ out) {
  out[0] = g_cost * (1.0f / (float)(BATCH*NPTS));
}

extern "C" void kernel_launch(void* const* d_in, const int* in_sizes, int n_in,
                              void* d_out, int out_size, void* d_ws, size_t ws_size,
                              hipStream_t stream) {
  const float* gen = (const float*)d_in[0];   // pc_gen [8,2048,3] f32
  const float* gt  = (const float*)d_in[1];   // pc_gt  [8,2048,3] f32
  float* out = (float*)d_out;

  const double L[10] = {-16384.0, -4096.0, -1024.0, -256.0, -64.0,
                        -16.0, -4.0, -1.0, -0.25, 0.0};
  float c[10];
  for (int i = 0; i < 10; ++i) c[i] = (float)(L[i] * 1.4426950408889634);

  k_init<<<64, 256, 0, stream>>>();
  k_a0<<<NBLK, TPB, 0, stream>>>(gen, gt, c[0]);
  for (int l = 0; l < 8; ++l) {
    k_cols<<<64, 256, 0, stream>>>();
    k_ca<false><<<NBLK, TPB, 0, stream>>>(gen, gt, c[l], c[l+1]);
  }
  k_cols<<<64, 256, 0, stream>>>();
  k_ca<true><<<NBLK, TPB, 0, stream>>>(gen, gt, c[8], 0.f);
  k_cols<<<64, 256, 0, stream>>>();
  k_c_last<<<NBLK, TPB, 0, stream>>>(gen, gt);
  k_final<<<1, 1, 0, stream>>>(out);
}

// Round 6
// 408.123 us; speedup vs baseline: 6.8040x; 1.0388x over previous
//
#include <hip/hip_runtime.h>
#include <math.h>

#define BATCH 8
#define NPTS 2048
#define MPTS 2048
#define TPB 512                       // 8 waves
#define RPB 16                        // rows per block
#define KC 4                          // columns per thread: 2048/512
#define ROUNDS 8                      // 2 rows per round
#define CHUNKS (NPTS/RPB)             // 128
#define NBLK (BATCH*CHUNKS)           // 1024

// Persistent state (re-initialized every kernel_launch -> deterministic).
__device__ float  g_remainl[BATCH*NPTS];
__device__ float  g_s[BATCH*NPTS];
__device__ float  g_remainr[BATCH*MPTS];
__device__ float  g_colsum[BATCH*MPTS];
__device__ float2 g_pr[BATCH*MPTS];   // (p = rr*ratio, rr_new)
__device__ float  g_cost;

#if __has_builtin(__builtin_amdgcn_exp2f)
#define EXP2(x) __builtin_amdgcn_exp2f(x)
#else
#define EXP2(x) exp2f(x)
#endif
#if __has_builtin(__builtin_amdgcn_sqrtf)
#define FSQRT(x) __builtin_amdgcn_sqrtf(x)
#else
#define FSQRT(x) sqrtf(x)
#endif

__global__ __launch_bounds__(256) void k_init() {
  int i = blockIdx.x*256 + threadIdx.x;   // 64 x 256
  g_remainl[i] = 1.0f;    // factorl = 1 (n == m)
  g_remainr[i] = 1.0f;
  g_colsum[i]  = 0.0f;
  if (i == 0) g_cost = 0.0f;
}

// B: column saturation; packs (p, rr_new); resets colsum.
__global__ __launch_bounds__(256) void k_cols() {
  const int i = blockIdx.x*256 + threadIdx.x;
  const float cs = g_colsum[i];
  const float rr = g_remainr[i];
  const float ratio = fminf(rr / (cs + 1e-9f), 1.0f);
  const float rrn = fmaxf(rr - cs*ratio, 0.0f);
  g_pr[i] = make_float2(rr*ratio, rrn);
  g_remainr[i] = rrn;
  g_colsum[i] = 0.0f;
}

// Each thread owns KC=4 fixed columns (register-resident). d2 via
// |g|^2+|c|^2-2g.c with per-row constants (-2gx,-2gy,-2gz,|g|^2) in LDS.
#define STAGE_COLS(NEED_PR)                                                \
  float cx[KC], cy[KC], cz[KC], rc2[KC], pp[KC], rrn[KC];                  \
  _Pragma("unroll")                                                        \
  for (int k = 0; k < KC; ++k) {                                           \
    const int m = t + TPB*k;                                               \
    const int gi = (b*MPTS + m)*3;                                         \
    cx[k] = gt[gi+0]; cy[k] = gt[gi+1]; cz[k] = gt[gi+2];                  \
    rc2[k] = cx[k]*cx[k] + cy[k]*cy[k] + cz[k]*cz[k];                      \
    if (NEED_PR) { const float2 pr = g_pr[b*MPTS + m];                     \
                   pp[k] = pr.x; rrn[k] = pr.y; }                          \
    else { pp[k] = 1.f; rrn[k] = 1.f; }                                    \
  }

#define STAGE_ROWS()                                                       \
  if (t < RPB) {                                                           \
    const int gi = (rowbase + t)*3;                                        \
    const float px = gen[gi+0], py = gen[gi+1], pz = gen[gi+2];            \
    rowdat[t] = make_float4(-2.f*px, -2.f*py, -2.f*pz,                     \
                            px*px + py*py + pz*pz);                        \
  }

#define D2(rd, k) fmaf(rd.x, cx[k], fmaf(rd.y, cy[k],                      \
                   fmaf(rd.z, cz[k], rd.w + rc2[k])))

// A-part for the first level (remainl = remainr = 1).
__global__ __launch_bounds__(TPB) void k_a0(const float* __restrict__ gen,
                                            const float* __restrict__ gt,
                                            float c1) {
  const int blk = blockIdx.x, b = blk >> 7, chunk = blk & (CHUNKS-1);
  const int t = threadIdx.x, wave = t >> 6, lane = t & 63;
  const int rowbase = b*NPTS + chunk*RPB;
  __shared__ float4 rowdat[RPB];
  __shared__ float  red[2][8];
  __shared__ float  scn_sh[2];
  STAGE_COLS(false)
  STAGE_ROWS()
  __syncthreads();
  float colacc[KC] = {0.f, 0.f, 0.f, 0.f};
  #pragma unroll 1
  for (int rr = 0; rr < ROUNDS; ++rr) {
    const float4 rd0 = rowdat[2*rr+0];
    const float4 rd1 = rowdat[2*rr+1];
    float w0[KC], w1[KC];
    float s1a = 0.f, s1b = 0.f;
    #pragma unroll
    for (int k = 0; k < KC; ++k) {
      const float ea = EXP2(c1*D2(rd0, k));
      const float eb = EXP2(c1*D2(rd1, k));
      w0[k] = ea; s1a += ea;
      w1[k] = eb; s1b += eb;
    }
    #pragma unroll
    for (int off = 1; off < 64; off <<= 1) {
      s1a += __shfl_xor(s1a, off);
      s1b += __shfl_xor(s1b, off);
    }
    if (lane == 0) { red[0][wave] = s1a; red[1][wave] = s1b; }
    __syncthreads();
    if (wave == 0 && lane < 2) {
      float s1t = 0.f;
      #pragma unroll
      for (int w = 0; w < 8; ++w) s1t += red[lane][w];
      const float scn = 1.0f / (s1t + 1e-9f);
      g_s[rowbase + 2*rr + lane] = scn;
      scn_sh[lane] = scn;
    }
    __syncthreads();
    const float scn0 = scn_sh[0], scn1 = scn_sh[1];
    #pragma unroll
    for (int k = 0; k < KC; ++k)
      colacc[k] = fmaf(w0[k], scn0, fmaf(w1[k], scn1, colacc[k]));
  }
  #pragma unroll
  for (int k = 0; k < KC; ++k)
    atomicAdd(&g_colsum[b*MPTS + t + TPB*k], colacc[k]);   // rr == 1
}

// Fused C(level l) + A(level l+1), 2 rows per barrier round.
// eq = exp2(cq*d2) is the NEXT level's weight; e1 = eq^4 (c1 = 4*cq exactly).
// LAST: next level is 0 -> eq = 1, colsum collapses to rrn * sum(scn).
template<bool LAST>
__global__ __launch_bounds__(TPB) void k_ca(const float* __restrict__ gen,
                                            const float* __restrict__ gt,
                                            float c1, float cq) {
  const int blk = blockIdx.x, b = blk >> 7, chunk = blk & (CHUNKS-1);
  const int t = threadIdx.x, wave = t >> 6, lane = t & 63;
  const int rowbase = b*NPTS + chunk*RPB;
  __shared__ float4 rowdat[RPB];
  __shared__ float  sc_s[RPB], rl_s[RPB];
  __shared__ float2 red[2][8];
  __shared__ float  scn_sh[2];
  __shared__ float  cred[8];
  STAGE_COLS(true)
  STAGE_ROWS()
  if (t < RPB) {
    sc_s[t] = g_s[rowbase + t];
    rl_s[t] = g_remainl[rowbase + t];
  }
  __syncthreads();
  float colacc[KC] = {0.f, 0.f, 0.f, 0.f};
  float costacc = 0.f, sumscn = 0.f;
  #pragma unroll 1
  for (int rr = 0; rr < ROUNDS; ++rr) {
    const float4 rd0 = rowdat[2*rr+0];
    const float4 rd1 = rowdat[2*rr+1];
    float w0[KC], w1[KC];
    float s1a = 0.f, rsa = 0.f, s2a = 0.f;
    float s1b = 0.f, rsb = 0.f, s2b = 0.f;
    #pragma unroll
    for (int k = 0; k < KC; ++k) {
      {
        const float d2 = D2(rd0, k);
        float e1, wq;
        if (LAST) { e1 = EXP2(c1*d2); wq = rrn[k]; }
        else { const float eq = EXP2(cq*d2); const float e2 = eq*eq;
               e1 = e2*e2; wq = eq*rrn[k]; }
        w0[k] = wq; rsa += wq;
        const float u = e1*pp[k];
        s1a += u;
        s2a = fmaf(u, FSQRT(fmaxf(d2, 1e-20f)), s2a);
      }
      {
        const float d2 = D2(rd1, k);
        float e1, wq;
        if (LAST) { e1 = EXP2(c1*d2); wq = rrn[k]; }
        else { const float eq = EXP2(cq*d2); const float e2 = eq*eq;
               e1 = e2*e2; wq = eq*rrn[k]; }
        w1[k] = wq; rsb += wq;
        const float u = e1*pp[k];
        s1b += u;
        s2b = fmaf(u, FSQRT(fmaxf(d2, 1e-20f)), s2b);
      }
    }
    costacc = fmaf(sc_s[2*rr+0], s2a, costacc);
    costacc = fmaf(sc_s[2*rr+1], s2b, costacc);
    #pragma unroll
    for (int off = 1; off < 64; off <<= 1) {
      s1a += __shfl_xor(s1a, off); rsa += __shfl_xor(rsa, off);
      s1b += __shfl_xor(s1b, off); rsb += __shfl_xor(rsb, off);
    }
    if (lane == 0) {
      red[0][wave] = make_float2(s1a, rsa);
      red[1][wave] = make_float2(s1b, rsb);
    }
    __syncthreads();
    if (wave == 0 && lane < 2) {
      float s1t = 0.f, rst = 0.f;
      #pragma unroll
      for (int w = 0; w < 8; ++w) {
        const float2 v = red[lane][w];
        s1t += v.x; rst += v.y;
      }
      const int r = 2*rr + lane, idx = rowbase + r;
      const float rl_new = fmaxf(rl_s[r] - sc_s[r]*s1t, 0.0f);
      const float scn = rl_new / (rst + 1e-9f);
      g_remainl[idx] = rl_new;
      g_s[idx] = scn;
      scn_sh[lane] = scn;
    }
    __syncthreads();
    const float scn0 = scn_sh[0], scn1 = scn_sh[1];
    if (LAST) {
      sumscn += scn0 + scn1;
    } else {
      #pragma unroll
      for (int k = 0; k < KC; ++k)
        colacc[k] = fmaf(w0[k], scn0, fmaf(w1[k], scn1, colacc[k]));
    }
  }
  if (LAST) {
    #pragma unroll
    for (int k = 0; k < KC; ++k)
      atomicAdd(&g_colsum[b*MPTS + t + TPB*k], rrn[k]*sumscn);
  } else {
    #pragma unroll
    for (int k = 0; k < KC; ++k)
      atomicAdd(&g_colsum[b*MPTS + t + TPB*k], colacc[k]);
  }
  // one cost reduction per block
  #pragma unroll
  for (int off = 1; off < 64; off <<= 1) costacc += __shfl_xor(costacc, off);
  if (lane == 0) cred[wave] = costacc;
  __syncthreads();
  if (t == 0) {
    float c = 0.f;
    #pragma unroll
    for (int w = 0; w < 8; ++w) c += cred[w];
    atomicAdd(&g_cost, c);
  }
}

// C-part of the final level (level == 0 -> weight = p, no exp, no butterflies
// in the row loop: cost deferred to one block-wide reduction).
__global__ __launch_bounds__(TPB) void k_c_last(const float* __restrict__ gen,
                                                const float* __restrict__ gt) {
  const int blk = blockIdx.x, b = blk >> 7, chunk = blk & (CHUNKS-1);
  const int t = threadIdx.x, wave = t >> 6, lane = t & 63;
  const int rowbase = b*NPTS + chunk*RPB;
  __shared__ float4 rowdat[RPB];
  __shared__ float  sc_s[RPB];
  __shared__ float  cred[8];
  STAGE_COLS(true)
  STAGE_ROWS()
  if (t < RPB) sc_s[t] = g_s[rowbase + t];
  __syncthreads();
  float costacc = 0.f;
  #pragma unroll 1
  for (int r = 0; r < RPB; ++r) {
    const float4 rd = rowdat[r];
    float s2 = 0.f;
    #pragma unroll
    for (int k = 0; k < KC; ++k)
      s2 = fmaf(pp[k], FSQRT(fmaxf(D2(rd, k), 1e-20f)), s2);
    costacc = fmaf(sc_s[r], s2, costacc);
  }
  #pragma unroll
  for (int off = 1; off < 64; off <<= 1) costacc += __shfl_xor(costacc, off);
  if (lane == 0) cred[wave] = costacc;
  __syncthreads();
  if (t == 0) {
    float c = 0.f;
    #pragma unroll
    for (int w = 0; w < 8; ++w) c += cred[w];
    atomicAdd(&g_cost, c);
  }
}

__global__ void k_final(float* __restrict__ out) {
  out[0] = g_cost * (1.0f / (float)(BATCH*NPTS));
}

extern "C" void kernel_launch(void* const* d_in, const int* in_sizes, int n_in,
                              void* d_out, int out_size, void* d_ws, size_t ws_size,
                              hipStream_t stream) {
  const float* gen = (const float*)d_in[0];   // pc_gen [8,2048,3] f32
  const float* gt  = (const float*)d_in[1];   // pc_gt  [8,2048,3] f32
  float* out = (float*)d_out;

  const double L[10] = {-16384.0, -4096.0, -1024.0, -256.0, -64.0,
                        -16.0, -4.0, -1.0, -0.25, 0.0};
  float c[10];
  for (int i = 0; i < 10; ++i) c[i] = (float)(L[i] * 1.4426950408889634);

  k_init<<<64, 256, 0, stream>>>();
  k_a0<<<NBLK, TPB, 0, stream>>>(gen, gt, c[0]);
  for (int l = 0; l < 8; ++l) {
    k_cols<<<64, 256, 0, stream>>>();
    k_ca<false><<<NBLK, TPB, 0, stream>>>(gen, gt, c[l], c[l+1]);
  }
  k_cols<<<64, 256, 0, stream>>>();
  k_ca<true><<<NBLK, TPB, 0, stream>>>(gen, gt, c[8], 0.f);
  k_cols<<<64, 256, 0, stream>>>();
  k_c_last<<<NBLK, TPB, 0, stream>>>(gen, gt);
  k_final<<<1, 1, 0, stream>>>(out);
}